// Round 1
// baseline (7029.539 us; speedup 1.0000x reference)
//
#include <hip/hip_runtime.h>
#include <hip/hip_bf16.h>
#include <stdint.h>
#include <stddef.h>

// NeuralODE: y' = MLP(y), Dormand-Prince 6-stage RK, 10 intervals x 4 substeps.
// Persistent kernel: 64 WGs x 16 batch rows, weights bf16-converted into d_ws
// and streamed from (XCD-local) L2 every eval. All matmuls as
// D = W(A) . act^T(B) with mfma_f32_16x16x32_bf16; RK state in registers.

typedef __bf16 bf16x8 __attribute__((ext_vector_type(8)));
typedef __bf16 bf16x4 __attribute__((ext_vector_type(4)));
typedef float  f32x4  __attribute__((ext_vector_type(4)));

#define DD 256
#define HH 512
#define MROWS 16
#define RA 264   // 256 + 8 pad (odd 16B-chunk count -> balanced LDS banks)
#define RH 520   // 512 + 8 pad

// ---- weight fp32 -> bf16 conversion (runs every launch; ws re-poisoned) ----
__global__ void cvt_w(const float* __restrict__ W1, const float* __restrict__ W2,
                      const float* __restrict__ W3, __bf16* __restrict__ o)
{
    int i = blockIdx.x * blockDim.x + threadIdx.x;  // 0 .. 524287
    float v;
    if (i < HH * DD)                 v = W1[i];
    else if (i < HH * DD + HH * HH)  v = W2[i - HH * DD];
    else                             v = W3[i - (HH * DD + HH * HH)];
    o[i] = (__bf16)v;
}

// One layer: acc[i] (i<NT tiles of 16 output-neurons) = W[ntile rows] x act^T.
// A-frag: lane reads W[n0+lr][kb*32+lg*8 ..+8] (contiguous, global/L2).
// B-frag: lane reads act[lr][kb*32+lg*8 ..+8]  (contiguous, LDS).
template<int K, int NT>
__device__ __forceinline__ void layer(const __bf16* __restrict__ W, int nbase,
                                      const __bf16* __restrict__ act, int rs,
                                      int lr, int lg, f32x4* acc)
{
#pragma unroll
    for (int i = 0; i < NT; ++i) { f32x4 z = {0.f, 0.f, 0.f, 0.f}; acc[i] = z; }
#pragma unroll
    for (int kb = 0; kb < K / 32; ++kb) {
        bf16x8 bfrag = *(const bf16x8*)(act + lr * rs + kb * 32 + lg * 8);
        const __bf16* wp = W + (size_t)(nbase + lr) * K + kb * 32 + lg * 8;
#pragma unroll
        for (int i = 0; i < NT; ++i) {
            bf16x8 afrag = *(const bf16x8*)(wp + (size_t)i * 16 * K);
            acc[i] = __builtin_amdgcn_mfma_f32_16x16x32_bf16(afrag, bfrag, acc[i], 0, 0, 0);
        }
    }
}

__global__ __launch_bounds__(512, 2)
void ode_kernel(const float* __restrict__ x0, const int* __restrict__ Tp,
                const __bf16* __restrict__ W1, const __bf16* __restrict__ W2,
                const __bf16* __restrict__ W3,
                const float* __restrict__ b1, const float* __restrict__ b2,
                const float* __restrict__ b3, float* __restrict__ out)
{
    __shared__ __bf16 sA [MROWS * RA];   // y_stage  [16][264] bf16
    __shared__ __bf16 sH1[MROWS * RH];   // h1       [16][520] bf16
    __shared__ __bf16 sH2[MROWS * RH];   // h2       [16][520] bf16

    const int   nT = *Tp - 1;
    const float hs = 10.0f / (float)nT * 0.25f;   // = T_TOTAL/(T-1)/SUBSTEPS

    const int tid  = threadIdx.x;
    const int wave = tid >> 6;
    const int lane = tid & 63;
    const int lr   = lane & 15;   // A-row / B-col / D-col index
    const int lg   = lane >> 4;   // k-group (0..3); D-rows = lg*4+j
    const int m0   = blockIdx.x * MROWS;
    const int row  = m0 + lr;     // this lane's batch row (for B/D roles)

    // ---- per-lane bias registers (static-indexed only) ----
    float bv1[4][4], bv2[4][4], bv3[2][4];
#pragma unroll
    for (int i = 0; i < 4; ++i)
#pragma unroll
        for (int j = 0; j < 4; ++j) {
            bv1[i][j] = b1[wave * 64 + i * 16 + lg * 4 + j];
            bv2[i][j] = b2[wave * 64 + i * 16 + lg * 4 + j];
        }
#pragma unroll
    for (int i = 0; i < 2; ++i)
#pragma unroll
        for (int j = 0; j < 4; ++j)
            bv3[i][j] = b3[wave * 32 + i * 16 + lg * 4 + j];

    // ---- RK state in registers: wave owns d-tiles {wave*2, wave*2+1} ----
    f32x4 yy[2];
#pragma unroll
    for (int i = 0; i < 2; ++i)
        yy[i] = *(const f32x4*)(x0 + (size_t)row * DD + wave * 32 + i * 16 + lg * 4);

    f32x4 k1v[2], k2v[2], k3v[2], k4v[2], k5v[2], k6v[2];

    __bf16* sAw  = sA  + lr * RA + wave * 32 + lg * 4;
    __bf16* sH1w = sH1 + lr * RH + wave * 64 + lg * 4;
    __bf16* sH2w = sH2 + lr * RH + wave * 64 + lg * 4;

    auto store_stage = [&](f32x4 a, f32x4 b) {
        bf16x4 v0, v1;
#pragma unroll
        for (int j = 0; j < 4; ++j) { v0[j] = (__bf16)a[j]; v1[j] = (__bf16)b[j]; }
        *(bf16x4*)(sAw)      = v0;
        *(bf16x4*)(sAw + 16) = v1;
    };

    auto mlp = [&](f32x4* kout) {
        __syncthreads();                       // sA fully written
        f32x4 acc[4];
        layer<DD, 4>(W1, wave * 64, sA, RA, lr, lg, acc);
#pragma unroll
        for (int i = 0; i < 4; ++i) {
            bf16x4 v;
#pragma unroll
            for (int j = 0; j < 4; ++j) v[j] = (__bf16)fmaxf(acc[i][j] + bv1[i][j], 0.0f);
            *(bf16x4*)(sH1w + i * 16) = v;
        }
        __syncthreads();                       // h1 ready
        layer<HH, 4>(W2, wave * 64, sH1, RH, lr, lg, acc);
#pragma unroll
        for (int i = 0; i < 4; ++i) {
            bf16x4 v;
#pragma unroll
            for (int j = 0; j < 4; ++j) v[j] = (__bf16)fmaxf(acc[i][j] + bv2[i][j], 0.0f);
            *(bf16x4*)(sH2w + i * 16) = v;
        }
        __syncthreads();                       // h2 ready
        f32x4 acc3[2];
        layer<HH, 2>(W3, wave * 32, sH2, RH, lr, lg, acc3);
#pragma unroll
        for (int i = 0; i < 2; ++i) {
            kout[i] = acc3[i];
#pragma unroll
            for (int j = 0; j < 4; ++j) kout[i][j] += bv3[i][j];
        }
    };

    for (int t = 0; t < nT; ++t) {
        for (int ss = 0; ss < 4; ++ss) {
            store_stage(yy[0], yy[1]);
            mlp(k1v);

            store_stage(yy[0] + hs * (0.2f * k1v[0]),
                        yy[1] + hs * (0.2f * k1v[1]));
            mlp(k2v);

            store_stage(yy[0] + hs * ((3.0f/40.0f)*k1v[0] + (9.0f/40.0f)*k2v[0]),
                        yy[1] + hs * ((3.0f/40.0f)*k1v[1] + (9.0f/40.0f)*k2v[1]));
            mlp(k3v);

            store_stage(yy[0] + hs * ((float)(44.0/45.0)*k1v[0] - (float)(56.0/15.0)*k2v[0]
                                     + (float)(32.0/9.0)*k3v[0]),
                        yy[1] + hs * ((float)(44.0/45.0)*k1v[1] - (float)(56.0/15.0)*k2v[1]
                                     + (float)(32.0/9.0)*k3v[1]));
            mlp(k4v);

            store_stage(yy[0] + hs * ((float)(19372.0/6561.0)*k1v[0] - (float)(25360.0/2187.0)*k2v[0]
                                     + (float)(64448.0/6561.0)*k3v[0] - (float)(212.0/729.0)*k4v[0]),
                        yy[1] + hs * ((float)(19372.0/6561.0)*k1v[1] - (float)(25360.0/2187.0)*k2v[1]
                                     + (float)(64448.0/6561.0)*k3v[1] - (float)(212.0/729.0)*k4v[1]));
            mlp(k5v);

            store_stage(yy[0] + hs * ((float)(9017.0/3168.0)*k1v[0] - (float)(355.0/33.0)*k2v[0]
                                     + (float)(46732.0/5247.0)*k3v[0] + (float)(49.0/176.0)*k4v[0]
                                     - (float)(5103.0/18656.0)*k5v[0]),
                        yy[1] + hs * ((float)(9017.0/3168.0)*k1v[1] - (float)(355.0/33.0)*k2v[1]
                                     + (float)(46732.0/5247.0)*k3v[1] + (float)(49.0/176.0)*k4v[1]
                                     - (float)(5103.0/18656.0)*k5v[1]));
            mlp(k6v);

#pragma unroll
            for (int i = 0; i < 2; ++i)
                yy[i] = yy[i] + hs * ((float)(35.0/384.0)*k1v[i] + (float)(500.0/1113.0)*k3v[i]
                                     + (float)(125.0/192.0)*k4v[i] + (float)(-2187.0/6784.0)*k5v[i]
                                     + (float)(11.0/84.0)*k6v[i]);
        }
        // emit y at interval end: out[b][t][d]
#pragma unroll
        for (int i = 0; i < 2; ++i)
            *(f32x4*)(out + ((size_t)row * nT + t) * DD + wave * 32 + i * 16 + lg * 4) = yy[i];
    }
}

extern "C" void kernel_launch(void* const* d_in, const int* in_sizes, int n_in,
                              void* d_out, int out_size, void* d_ws, size_t ws_size,
                              hipStream_t stream)
{
    const float* x0 = (const float*)d_in[0];
    const int*   Tp = (const int*)  d_in[1];
    const float* W1 = (const float*)d_in[2];
    const float* b1 = (const float*)d_in[3];
    const float* W2 = (const float*)d_in[4];
    const float* b2 = (const float*)d_in[5];
    const float* W3 = (const float*)d_in[6];
    const float* b3 = (const float*)d_in[7];

    const int B = in_sizes[0] / DD;          // 1024

    __bf16* wb = (__bf16*)d_ws;              // 1 MiB: W1b | W2b | W3b
    const int nconv = HH * DD + HH * HH + DD * HH;   // 524288
    cvt_w<<<nconv / 256, 256, 0, stream>>>(W1, W2, W3, wb);

    ode_kernel<<<B / MROWS, 512, 0, stream>>>(x0, Tp,
                                              wb, wb + HH * DD, wb + HH * DD + HH * HH,
                                              b1, b2, b3, (float*)d_out);
}